// Round 11
// baseline (522.429 us; speedup 1.0000x reference)
//
#include <hip/hip_runtime.h>
#include <hip/hip_fp16.h>

#define HEADS 8
#define F_IN 256
#define OUT 64
#define NOUT 512   // HEADS*OUT
#define CAP 1024   // staged edges per wave (16 rows * avg deg 32 = ~512; 22-sigma headroom)
#define CAPP (CAP + 16)  // padded: prologue may over-read up to ~11 entries

// bucket-sort CSR build params
#define RPB 128    // rows per bucket (pow2); lrow fits 7 bits
#define MAXB 512   // max buckets; N/RPB = 391 for N=50000 (requires N <= 65536)
#define CHA 8192   // edges per bscatter block

typedef __attribute__((ext_vector_type(8))) _Float16 f16x8;
typedef __attribute__((ext_vector_type(2))) _Float16 f16x2;
typedef __attribute__((ext_vector_type(4))) float f32x4;

__device__ __forceinline__ short f2h(float f) {
  _Float16 h = (_Float16)f;
  return *(short*)&h;
}
__device__ __forceinline__ f16x2 u2h2(unsigned u) {
  union { unsigned u; f16x2 h; } x; x.u = u; return x.h;
}
__device__ __forceinline__ float h2f(unsigned short b) {
  _Float16 h = *(_Float16*)&b; return (float)h;
}

// ---------------------------------------------------------------------------
// Convert f32 -> f16 bits, 8 elems/thread
// ---------------------------------------------------------------------------
__global__ __launch_bounds__(256) void conv_kernel(
    const float* __restrict__ src, short* __restrict__ dst, int n8)
{
  int i = blockIdx.x * 256 + threadIdx.x;
  if (i >= n8) return;
  const float4 a = *(const float4*)(src + (size_t)i * 8);
  const float4 b = *(const float4*)(src + (size_t)i * 8 + 4);
  short r[8] = { f2h(a.x), f2h(a.y), f2h(a.z), f2h(a.w),
                 f2h(b.x), f2h(b.y), f2h(b.z), f2h(b.w) };
  *(uint4*)(dst + (size_t)i * 8) = *(uint4*)r;
}

// ---------------------------------------------------------------------------
// va[h][k] = sum_o W2[h*64+o][k] * As[h][OUT+o]  (f16 pairs for fdot2).
// Softmax shift-invariance: Al cancels per-row; global-max shift dropped
// (Ar ~ N(0,1); exp range safe in f32 by >20 sigma).
// ---------------------------------------------------------------------------
__global__ __launch_bounds__(256) void va_kernel(
    const short* __restrict__ W2, const float* __restrict__ As,
    unsigned short* __restrict__ va16)
{
  const int h = blockIdx.x, k = threadIdx.x;
  const unsigned short* W = (const unsigned short*)W2;
  float s = 0.f;
  #pragma unroll 8
  for (int o = 0; o < OUT; ++o)
    s += h2f(W[(size_t)(h * OUT + o) * F_IN + k]) * As[h * 2 * OUT + OUT + o];
  va16[h * F_IN + k] = (unsigned short)f2h(s);
}

// ---------------------------------------------------------------------------
// Wf[n][h] = exp(x[n].va[h] + arb[h])  -- fused GEMV + exp, f32 weights.
// ---------------------------------------------------------------------------
__global__ __launch_bounds__(256) void argemv_kernel(
    const short* __restrict__ xh, const unsigned short* __restrict__ va16,
    const float* __restrict__ Asb, float* __restrict__ Wf, int N)
{
  __shared__ unsigned vas[8][132];   // [h][pair]; pad 128->132: bank = (4h+p)%32
  for (int i = threadIdx.x; i < 1024; i += 256)
    vas[i >> 7][i & 127] = ((const unsigned*)va16)[i];
  __syncthreads();
  const int t = blockIdx.x * 256 + threadIdx.x;
  const int n = t >> 3, h = t & 7;
  if (n >= N) return;
  const unsigned short* xr = (const unsigned short*)xh + (size_t)n * F_IN;
  float acc = 0.f;
  #pragma unroll
  for (int kk = 0; kk < F_IN; kk += 8) {
    const uint4 xv = *(const uint4*)(xr + kk);
    const int p2 = kk >> 1;
    acc = __builtin_amdgcn_fdot2(u2h2(xv.x), u2h2(vas[h][p2]),     acc, false);
    acc = __builtin_amdgcn_fdot2(u2h2(xv.y), u2h2(vas[h][p2 + 1]), acc, false);
    acc = __builtin_amdgcn_fdot2(u2h2(xv.z), u2h2(vas[h][p2 + 2]), acc, false);
    acc = __builtin_amdgcn_fdot2(u2h2(xv.w), u2h2(vas[h][p2 + 3]), acc, false);
  }
  Wf[t] = __expf(acc + Asb[h * 2 + 1]);
}

// ---------------------------------------------------------------------------
// MFMA GEMM (f16): writes u PRE-SCALED by w[n][h], SLICE-MAJOR u[hp][N+1][32]
// (row N of each slice = zeroed dummy for agg's maskless tail handling).
// XCD-aware remap: bid&7 = XCD owns a CONTIGUOUS row-range for ALL 8 heads.
// ---------------------------------------------------------------------------
__global__ __launch_bounds__(256) void gemm_mfma(
    const short* __restrict__ xh, const short* __restrict__ W2,
    const float* __restrict__ Wf, short* __restrict__ u, int N)
{
  __shared__ __align__(16) short as[128][72];  // 144B row stride: 2-way bank alias (free)
  __shared__ __align__(16) short bs[64][72];
  const int ytiles = (N + 127) / 128;
  const int YB = (ytiles + 7) / 8;
  const int bid = blockIdx.x;
  const int xcd = bid & 7;
  const int j   = bid >> 3;
  const int h   = j & 7;
  const int yt  = xcd * YB + (j >> 3);
  if (yt >= ytiles) return;
  const int n0 = yt * 128;
  const int NP1 = N + 1;
  const int tid = threadIdx.x;
  const int lane = tid & 63, wave = tid >> 6;
  const int lcol = lane & 15, quad = lane >> 4;
  const int m0 = wave * 32;
  const short* Wh = W2 + h * OUT * F_IN;

  f32x4 acc[2][4] = {};

  for (int k0 = 0; k0 < F_IN; k0 += 64) {
    __syncthreads();
    #pragma unroll
    for (int p = 0; p < 4; ++p) {
      int id = tid + 256 * p;
      int r = id >> 3, s = id & 7;
      int n = n0 + r;
      uint4 v = make_uint4(0, 0, 0, 0);
      if (n < N) v = *(const uint4*)(xh + (size_t)n * F_IN + k0 + s * 8);
      *(uint4*)&as[r][s * 8] = v;
    }
    #pragma unroll
    for (int p = 0; p < 2; ++p) {
      int id = tid + 256 * p;
      int r = id >> 3, s = id & 7;
      uint4 v = *(const uint4*)(Wh + r * F_IN + k0 + s * 8);
      *(uint4*)&bs[r][s * 8] = v;
    }
    __syncthreads();
    #pragma unroll
    for (int ks = 0; ks < 2; ++ks) {
      f16x8 af[2], bf[4];
      #pragma unroll
      for (int i = 0; i < 2; ++i)
        af[i] = *(const f16x8*)&as[m0 + i * 16 + lcol][ks * 32 + quad * 8];
      #pragma unroll
      for (int jj = 0; jj < 4; ++jj)
        bf[jj] = *(const f16x8*)&bs[jj * 16 + lcol][ks * 32 + quad * 8];
      #pragma unroll
      for (int i = 0; i < 2; ++i)
        #pragma unroll
        for (int jj = 0; jj < 4; ++jj)
          acc[i][jj] = __builtin_amdgcn_mfma_f32_16x16x32_f16(
              af[i], bf[jj], acc[i][jj], 0, 0, 0);
    }
  }

  // epilogue: u = f16(acc * w[n][h]), slice-major with N+1 stride
  #pragma unroll
  for (int i = 0; i < 2; ++i) {
    #pragma unroll
    for (int reg = 0; reg < 4; ++reg) {
      int n = n0 + m0 + i * 16 + quad * 4 + reg;
      if (n < N) {
        const float w = Wf[(size_t)n * 8 + h];
        #pragma unroll
        for (int jj = 0; jj < 4; ++jj) {
          const int hp = h * 2 + (jj >> 1);
          u[((size_t)hp * NP1 + n) * 32 + (jj & 1) * 16 + lcol] =
              f2h(acc[i][jj][reg] * w);
        }
      }
    }
  }
}

// ---------------------------------------------------------------------------
// Zero the 16 per-slice dummy rows (index N of each slice). Must run after
// bsort (packed records alias u) and before agg.
// ---------------------------------------------------------------------------
__global__ __launch_bounds__(64) void zdum_kernel(short* __restrict__ u, int N)
{
  const int t = threadIdx.x;          // 64 threads = 16 slices x 4 uint4
  const int hp = t >> 2, q = t & 3;
  *(uint4*)(u + ((size_t)hp * (N + 1) + N) * 32 + q * 8) = make_uint4(0, 0, 0, 0);
}

// ---------------------------------------------------------------------------
// CSR build v2: bucket sort (line-dense writes; R8's atomic scatter had 16x
// write amplification).
// ---------------------------------------------------------------------------
__global__ __launch_bounds__(256) void bcount_kernel(
    const int* __restrict__ row, int* __restrict__ bcnt, int E)
{
  __shared__ int h[MAXB];
  for (int i = threadIdx.x; i < MAXB; i += 256) h[i] = 0;
  __syncthreads();
  for (int e = blockIdx.x * 256 + threadIdx.x; e < E; e += gridDim.x * 256)
    atomicAdd(&h[row[e] >> 7], 1);
  __syncthreads();
  for (int i = threadIdx.x; i < MAXB; i += 256) {
    int v = h[i];
    if (v) atomicAdd(&bcnt[i], v);
  }
}

__global__ __launch_bounds__(MAXB) void bscan_kernel(
    const int* __restrict__ bcnt, int* __restrict__ bofs,
    int* __restrict__ gcur, int* __restrict__ rowptr_last, int E, int NB)
{
  __shared__ int sd[MAXB];
  const int t = threadIdx.x;
  int v = (t < NB) ? bcnt[t] : 0;
  sd[t] = v;
  __syncthreads();
  for (int off = 1; off < MAXB; off <<= 1) {
    int u = (t >= off) ? sd[t - off] : 0;
    __syncthreads();
    sd[t] += u;
    __syncthreads();
  }
  int excl = sd[t] - v;
  if (t < NB) { bofs[t] = excl; gcur[t] = excl; }
  if (t == NB - 1) bofs[NB] = excl + v;   // == E
  if (t == 0) rowptr_last[0] = E;
}

__global__ __launch_bounds__(256) void bscatter_kernel(
    const int* __restrict__ row, const int* __restrict__ col,
    int* __restrict__ gcur, unsigned* __restrict__ packed, int E)
{
  __shared__ int h[MAXB];
  __shared__ int base[MAXB];
  const int lo = blockIdx.x * CHA;
  const int hi = min(lo + CHA, E);
  for (int i = threadIdx.x; i < MAXB; i += 256) h[i] = 0;
  __syncthreads();
  for (int e = lo + threadIdx.x; e < hi; e += 256)
    atomicAdd(&h[row[e] >> 7], 1);
  __syncthreads();
  for (int i = threadIdx.x; i < MAXB; i += 256) {
    int v = h[i];
    base[i] = v ? atomicAdd(&gcur[i], v) : 0;
    h[i] = 0;
  }
  __syncthreads();
  for (int e = lo + threadIdx.x; e < hi; e += 256) {
    int r = row[e];
    int b = r >> 7;
    int p = base[b] + atomicAdd(&h[b], 1);
    packed[p] = ((unsigned)(r & (RPB - 1)) << 16) | (unsigned)col[e];
  }
}

__global__ __launch_bounds__(256) void bsort_kernel(
    const unsigned* __restrict__ packed, const int* __restrict__ bofs,
    int* __restrict__ row_ptr, int* __restrict__ col_sorted, int N)
{
  __shared__ int h[RPB];
  __shared__ int sd[RPB];
  __shared__ int cur[RPB];
  const int b = blockIdx.x;
  const int lo = bofs[b], hi = bofs[b + 1];
  const int t = threadIdx.x;
  if (t < RPB) h[t] = 0;
  __syncthreads();
  for (int i = lo + t; i < hi; i += 256)
    atomicAdd(&h[packed[i] >> 16], 1);
  __syncthreads();
  if (t < RPB) sd[t] = h[t];
  __syncthreads();
  for (int off = 1; off < RPB; off <<= 1) {
    int u = (t >= off && t < RPB) ? sd[t - off] : 0;
    __syncthreads();
    if (t < RPB) sd[t] += u;
    __syncthreads();
  }
  if (t < RPB) {
    int excl = sd[t] - h[t];
    cur[t] = lo + excl;
    int r = b * RPB + t;
    if (r < N) row_ptr[r] = lo + excl;
  }
  __syncthreads();
  for (int i = lo + t; i < hi; i += 256) {
    unsigned u = packed[i];
    int p = atomicAdd(&cur[u >> 16], 1);
    col_sorted[p] = (int)(u & 0xffffu);
  }
}

// ---------------------------------------------------------------------------
// Denominator SpMV: swb[n][8] = sum_{j in N(n)} w[.][j]. Wf is 1.6MB ->
// L2-resident on every XCD; lane-per-edge, f32 accumulate, full-wave reduce.
// ---------------------------------------------------------------------------
__global__ __launch_bounds__(256) void sw_kernel(
    const int* __restrict__ row_ptr, const int* __restrict__ col_sorted,
    const float* __restrict__ Wf, float* __restrict__ swb, int N)
{
  const int lane = threadIdx.x & 63;
  const int wave = threadIdx.x >> 6;
  const int row = blockIdx.x * 4 + wave;
  if (row >= N) return;
  const int start = row_ptr[row], end = row_ptr[row + 1];
  float a[8];
  #pragma unroll
  for (int i = 0; i < 8; ++i) a[i] = 0.f;
  for (int e = start + lane; e < end; e += 64) {
    int c = col_sorted[e];
    const float4 v0 = *(const float4*)(Wf + (size_t)c * 8);
    const float4 v1 = *(const float4*)(Wf + (size_t)c * 8 + 4);
    a[0] += v0.x; a[1] += v0.y; a[2] += v0.z; a[3] += v0.w;
    a[4] += v1.x; a[5] += v1.y; a[6] += v1.z; a[7] += v1.w;
  }
  #pragma unroll
  for (int off = 1; off <= 32; off <<= 1) {
    #pragma unroll
    for (int i = 0; i < 8; ++i) a[i] += __shfl_xor(a[i], off);
  }
  if (lane == 0) {
    float* sp = swb + (size_t)row * 8;
    *(float4*)sp       = make_float4(a[0], a[1], a[2], a[3]);
    *((float4*)sp + 1) = make_float4(a[4], a[5], a[6], a[7]);
  }
}

// ---------------------------------------------------------------------------
// Aggregation half-kernel: out[:, head, p*32:(p+1)*32] for head = blockIdx&7.
// Residency (R4): premultiplied u; per-XCD high-rate set = 3.2MB slice < 4MB.
// Work-per-wave (R5/R7): 16 rows/wave, one row per 4-lane group.
// LDS-staged indices (R8): wave's window staged with coalesced nt loads.
// NEW (R11): maskless inner loop via per-slice DUMMY ROW at index N --
// overrun/tail edges select index N (1 cndmask/edge), gather zeros, and the
// consume is pure perm+fdot2 (no AND masks, no clamp-mins). 4-edge stages,
// depth-2 ping-pong = 8 gathers in flight.
// ---------------------------------------------------------------------------
__global__ __launch_bounds__(256) void agg_kernel(
    const int* __restrict__ row_ptr, const int* __restrict__ col_sorted,
    const unsigned short* __restrict__ u, const float* __restrict__ swb,
    const float* __restrict__ Wb, float* __restrict__ out, int N, int p)
{
  __shared__ int ec[4][CAPP];
  const int lane = threadIdx.x & 63;
  const int wave = threadIdx.x >> 6;
  const int head = blockIdx.x & 7;               // XCD pin (round-robin %8)
  const int g = lane >> 2, sub = lane & 3;
  const int rbase = ((blockIdx.x >> 3) * 4 + wave) * 16;
  const int row = rbase + g;
  const bool valid = row < N;
  const int NP1 = N + 1;

  // stage the wave's contiguous edge window into LDS (coalesced nt loads)
  const int wstart = row_ptr[min(rbase, N)];
  const int wend   = row_ptr[min(rbase + 16, N)];
  const int wlen = wend - wstart;
  const int nst = min(wlen, CAP);
  int* lds = ec[wave];
  for (int i = lane; i < nst; i += 64)
    lds[i] = __builtin_nontemporal_load(col_sorted + wstart + i);
  __syncthreads();

  const int sg = valid ? row_ptr[row]     : 0;
  const int eg = valid ? row_ptr[row + 1] : 0;
  const int deg = eg - sg;
  const unsigned short* ub =
      u + ((size_t)(head * 2 + p) * NP1) * 32 + (sub << 3);

  float acc[8];
  #pragma unroll
  for (int i = 0; i < 8; ++i) acc[i] = 0.f;
  const f16x2 ones = {(_Float16)1.0f, (_Float16)1.0f};

  if (wlen <= CAP) {
    const int lsg = valid ? sg - wstart : 0;
    const int nstg = (deg + 3) >> 2;          // 4-edge stages
    const int nstg2 = max(2, (nstg + 1) & ~1);

    auto loadQ = [&](int s, int* c) {
      const int b = lsg + 4 * s;
      #pragma unroll
      for (int k = 0; k < 4; ++k) {
        int v = lds[b + k];                  // padded array: safe over-read
        c[k] = (4 * s + k < deg) ? v : N;    // dummy row for overrun
      }
    };
    auto issueQ = [&](const int* c, uint4* v) {
      #pragma unroll
      for (int k = 0; k < 4; ++k)
        v[k] = *(const uint4*)(ub + (size_t)c[k] * 32);
    };
    auto consumeQ = [&](const uint4* v) {
      #pragma unroll
      for (int pp = 0; pp < 2; ++pp) {
        unsigned a1[4] = { v[2*pp].x, v[2*pp].y, v[2*pp].z, v[2*pp].w };
        unsigned a2[4] = { v[2*pp+1].x, v[2*pp+1].y, v[2*pp+1].z, v[2*pp+1].w };
        #pragma unroll
        for (int q = 0; q < 4; ++q) {
          unsigned plo = __builtin_amdgcn_perm(a2[q], a1[q], 0x05040100u);
          unsigned phi = __builtin_amdgcn_perm(a2[q], a1[q], 0x07060302u);
          acc[2 * q]     = __builtin_amdgcn_fdot2(u2h2(plo), ones, acc[2 * q],     false);
          acc[2 * q + 1] = __builtin_amdgcn_fdot2(u2h2(phi), ones, acc[2 * q + 1], false);
        }
      }
    };

    int cA[4], cB[4];
    uint4 vA[4], vB[4];
    loadQ(0, cA); issueQ(cA, vA);
    loadQ(1, cB); issueQ(cB, vB);
    int s = 0;
    for (; s + 2 < nstg2; s += 2) {
      consumeQ(vA);
      loadQ(s + 2, cA); issueQ(cA, vA);
      consumeQ(vB);
      loadQ(s + 3, cB); issueQ(cB, vB);
    }
    consumeQ(vA);
    consumeQ(vB);
  } else {
    // fallback (window > CAP; statistically impossible but correct)
    const int np = (deg + 1) >> 1;
    for (int j = 0; j < np; ++j) {
      const int e1 = sg + 2 * j, e2 = e1 + 1;
      const int c1 = (e1 < eg) ? __builtin_nontemporal_load(col_sorted + e1) : N;
      const int c2 = (e2 < eg) ? __builtin_nontemporal_load(col_sorted + e2) : N;
      const uint4 v1 = *(const uint4*)(ub + (size_t)c1 * 32);
      const uint4 v2 = *(const uint4*)(ub + (size_t)c2 * 32);
      unsigned a1[4] = { v1.x, v1.y, v1.z, v1.w };
      unsigned a2[4] = { v2.x, v2.y, v2.z, v2.w };
      #pragma unroll
      for (int q = 0; q < 4; ++q) {
        unsigned plo = __builtin_amdgcn_perm(a2[q], a1[q], 0x05040100u);
        unsigned phi = __builtin_amdgcn_perm(a2[q], a1[q], 0x07060302u);
        acc[2 * q]     = __builtin_amdgcn_fdot2(u2h2(plo), ones, acc[2 * q],     false);
        acc[2 * q + 1] = __builtin_amdgcn_fdot2(u2h2(phi), ones, acc[2 * q + 1], false);
      }
    }
  }

  if (valid) {
    const float sw = swb[(size_t)row * 8 + head];
    const float inv = (sw > 0.f) ? 1.f / sw : 0.f;
    const int bidx = head * OUT + p * 32 + (sub << 3);
    const float4 b0 = *(const float4*)(Wb + bidx);
    const float4 b1 = *(const float4*)(Wb + bidx + 4);
    const float bb[8] = { b0.x, b0.y, b0.z, b0.w, b1.x, b1.y, b1.z, b1.w };
    float r[8];
    #pragma unroll
    for (int i = 0; i < 8; ++i) {
      float y = acc[i] * inv + bb[i];
      r[i] = (y > 0.f) ? y : (__expf(y) - 1.f);
    }
    f32x4* op = (f32x4*)(out + (size_t)row * NOUT + bidx);
    f32x4 o0 = { r[0], r[1], r[2], r[3] };
    f32x4 o1 = { r[4], r[5], r[6], r[7] };
    __builtin_nontemporal_store(o0, op);
    __builtin_nontemporal_store(o1, op + 1);
  }
}

// ---------------------------------------------------------------------------
extern "C" void kernel_launch(void* const* d_in, const int* in_sizes, int n_in,
                              void* d_out, int out_size, void* d_ws, size_t ws_size,
                              hipStream_t stream)
{
  const float* x    = (const float*)d_in[0];
  const int*   erow = (const int*)d_in[1];
  const int*   ecol = (const int*)d_in[2];
  const float* Ws   = (const float*)d_in[3];
  const float* Wb   = (const float*)d_in[4];
  const float* As   = (const float*)d_in[5];
  const float* Asb  = (const float*)d_in[6];
  float* out = (float*)d_out;
  const int N = in_sizes[0] / F_IN;
  const int E = in_sizes[1];

  char* p = (char*)d_ws;
  short* u       = (short*)p; p += (size_t)16 * (N + 1) * 32 * sizeof(short);
  short* xh      = (short*)p; p += (size_t)N * F_IN * sizeof(short);
  short* W2      = (short*)p; p += (size_t)NOUT * F_IN * sizeof(short);
  unsigned short* va16 = (unsigned short*)p; p += (size_t)HEADS * F_IN * sizeof(short);
  float* Wf      = (float*)p; p += (size_t)N * HEADS * sizeof(float);
  float* swb     = (float*)p; p += (size_t)N * HEADS * sizeof(float);
  int* row_ptr   = (int*)p;   p += (size_t)(N + 1) * sizeof(int);
  int* bcnt      = (int*)p;   p += MAXB * sizeof(int);
  int* bofs      = (int*)p;   p += (MAXB + 1) * sizeof(int);
  int* gcur      = (int*)p;   p += MAXB * sizeof(int);
  int* col_sorted= (int*)p;   p += (size_t)E * sizeof(int);
  // packed records alias u: dead before gemm_mfma/zdum write u (same stream)
  unsigned* packed = (unsigned*)u;

  const int NB = (N + RPB - 1) / RPB;   // 391 for N=50000 (<= MAXB)

  (void)hipMemsetAsync(bcnt, 0, MAXB * sizeof(int), stream);

  // CSR build v2 (bucket sort, line-dense writes)
  bcount_kernel<<<dim3(512), dim3(256), 0, stream>>>(erow, bcnt, E);
  bscan_kernel<<<dim3(1), dim3(MAXB), 0, stream>>>(
      bcnt, bofs, gcur, row_ptr + N, E, NB);
  bscatter_kernel<<<dim3((E + CHA - 1) / CHA), dim3(256), 0, stream>>>(
      erow, ecol, gcur, packed, E);
  bsort_kernel<<<dim3(NB), dim3(256), 0, stream>>>(
      packed, bofs, row_ptr, col_sorted, N);
  // zero per-slice dummy rows (after bsort: packed aliases u)
  zdum_kernel<<<dim3(1), dim3(64), 0, stream>>>(u, N);

  // f16 conversions
  conv_kernel<<<dim3((N * F_IN / 8 + 255) / 256), dim3(256), 0, stream>>>(
      x, xh, N * F_IN / 8);
  conv_kernel<<<dim3((NOUT * F_IN / 8 + 255) / 256), dim3(256), 0, stream>>>(
      Ws, W2, NOUT * F_IN / 8);

  // attention weights first (GEMV + exp; no max-shift needed)
  va_kernel<<<dim3(HEADS), dim3(F_IN), 0, stream>>>(W2, As, va16);
  argemv_kernel<<<dim3((N * HEADS + 255) / 256), dim3(256), 0, stream>>>(
      xh, va16, Asb, Wf, N);

  // MFMA GEMM -> pre-scaled u (slice-major, N+1 stride), XCD row-sliced
  const int ytiles = (N + 127) / 128;
  const int YB = (ytiles + 7) / 8;
  gemm_mfma<<<dim3(8 * 8 * YB), dim3(256), 0, stream>>>(xh, W2, Wf, u, N);

  // denominators
  sw_kernel<<<dim3((N + 3) / 4), dim3(256), 0, stream>>>(
      row_ptr, col_sorted, Wf, swb, N);

  // aggregation: two sequential half-kernels, head->XCD pinned,
  // 16 rows per wave, LDS-staged indices, maskless dummy-row inner loop
  const int nblk = 8 * ((N + 63) / 64);
  agg_kernel<<<dim3(nblk), dim3(256), 0, stream>>>(
      row_ptr, col_sorted, (const unsigned short*)u, swb, Wb, out, N, 0);
  agg_kernel<<<dim3(nblk), dim3(256), 0, stream>>>(
      row_ptr, col_sorted, (const unsigned short*)u, swb, Wb, out, N, 1);
}

// Round 12
// 486.897 us; speedup vs baseline: 1.0730x; 1.0730x over previous
//
#include <hip/hip_runtime.h>
#include <hip/hip_fp16.h>

#define HEADS 8
#define F_IN 256
#define OUT 64
#define NOUT 512   // HEADS*OUT
#define CAP 1024   // staged edges per wave (16 rows * avg deg 32 = ~512; 22-sigma headroom)
#define CAPP (CAP + 16)  // padded: pipeline may over-read a couple entries

// bucket-sort CSR build params
#define RPB 128    // rows per bucket (pow2); lrow fits 7 bits
#define MAXB 512   // max buckets; N/RPB = 391 for N=50000 (requires N <= 65536)
#define CHA 8192   // edges per bscatter block

typedef __attribute__((ext_vector_type(8))) _Float16 f16x8;
typedef __attribute__((ext_vector_type(2))) _Float16 f16x2;
typedef __attribute__((ext_vector_type(4))) float f32x4;

__device__ __forceinline__ short f2h(float f) {
  _Float16 h = (_Float16)f;
  return *(short*)&h;
}
__device__ __forceinline__ f16x2 u2h2(unsigned u) {
  union { unsigned u; f16x2 h; } x; x.u = u; return x.h;
}
__device__ __forceinline__ float h2f(unsigned short b) {
  _Float16 h = *(_Float16*)&b; return (float)h;
}

// ---------------------------------------------------------------------------
// Convert f32 -> f16 bits, 8 elems/thread
// ---------------------------------------------------------------------------
__global__ __launch_bounds__(256) void conv_kernel(
    const float* __restrict__ src, short* __restrict__ dst, int n8)
{
  int i = blockIdx.x * 256 + threadIdx.x;
  if (i >= n8) return;
  const float4 a = *(const float4*)(src + (size_t)i * 8);
  const float4 b = *(const float4*)(src + (size_t)i * 8 + 4);
  short r[8] = { f2h(a.x), f2h(a.y), f2h(a.z), f2h(a.w),
                 f2h(b.x), f2h(b.y), f2h(b.z), f2h(b.w) };
  *(uint4*)(dst + (size_t)i * 8) = *(uint4*)r;
}

// ---------------------------------------------------------------------------
// MFMA GEMM (f16) with FUSED attention weight: epilogue computes
// ar[n][h] = sum_o t[n][h][o]*As_r[h][o] via in-register reduction (shfl over
// the 16 lcol lanes), w = exp(ar + arb)  [shift-free softmax: Al cancels
// per-row; Ar ~ N(0,1), f32 exp safe by >20 sigma], then writes
// u = f16(t*w) SLICE-MAJOR u[hp][N+1][32] (row N = zeroed dummy for agg's
// maskless tails) and Wf[n][h] = w for the denominator SpMV.
// XCD-aware remap: bid&7 = XCD owns a CONTIGUOUS row-range for ALL 8 heads.
// ---------------------------------------------------------------------------
__global__ __launch_bounds__(256) void gemm_mfma(
    const short* __restrict__ xh, const short* __restrict__ W2,
    const float* __restrict__ As, const float* __restrict__ Asb,
    float* __restrict__ Wf, short* __restrict__ u, int N)
{
  __shared__ __align__(16) short as[128][72];  // 144B row stride: 2-way bank alias (free)
  __shared__ __align__(16) short bs[64][72];
  const int ytiles = (N + 127) / 128;
  const int YB = (ytiles + 7) / 8;
  const int bid = blockIdx.x;
  const int xcd = bid & 7;
  const int j   = bid >> 3;
  const int h   = j & 7;
  const int yt  = xcd * YB + (j >> 3);
  if (yt >= ytiles) return;
  const int n0 = yt * 128;
  const int NP1 = N + 1;
  const int tid = threadIdx.x;
  const int lane = tid & 63, wave = tid >> 6;
  const int lcol = lane & 15, quad = lane >> 4;
  const int m0 = wave * 32;
  const short* Wh = W2 + h * OUT * F_IN;

  f32x4 acc[2][4] = {};

  for (int k0 = 0; k0 < F_IN; k0 += 64) {
    __syncthreads();
    #pragma unroll
    for (int p = 0; p < 4; ++p) {
      int id = tid + 256 * p;
      int r = id >> 3, s = id & 7;
      int n = n0 + r;
      uint4 v = make_uint4(0, 0, 0, 0);
      if (n < N) v = *(const uint4*)(xh + (size_t)n * F_IN + k0 + s * 8);
      *(uint4*)&as[r][s * 8] = v;
    }
    #pragma unroll
    for (int p = 0; p < 2; ++p) {
      int id = tid + 256 * p;
      int r = id >> 3, s = id & 7;
      uint4 v = *(const uint4*)(Wh + r * F_IN + k0 + s * 8);
      *(uint4*)&bs[r][s * 8] = v;
    }
    __syncthreads();
    #pragma unroll
    for (int ks = 0; ks < 2; ++ks) {
      f16x8 af[2], bf[4];
      #pragma unroll
      for (int i = 0; i < 2; ++i)
        af[i] = *(const f16x8*)&as[m0 + i * 16 + lcol][ks * 32 + quad * 8];
      #pragma unroll
      for (int jj = 0; jj < 4; ++jj)
        bf[jj] = *(const f16x8*)&bs[jj * 16 + lcol][ks * 32 + quad * 8];
      #pragma unroll
      for (int i = 0; i < 2; ++i)
        #pragma unroll
        for (int jj = 0; jj < 4; ++jj)
          acc[i][jj] = __builtin_amdgcn_mfma_f32_16x16x32_f16(
              af[i], bf[jj], acc[i][jj], 0, 0, 0);
    }
  }

  // epilogue: ar -> w -> u = f16(acc*w), slice-major with N+1 stride
  float arw_l[4];
  #pragma unroll
  for (int jj = 0; jj < 4; ++jj) arw_l[jj] = As[h * 2 * OUT + OUT + jj * 16 + lcol];
  const float arb = Asb[h * 2 + 1];
  #pragma unroll
  for (int i = 0; i < 2; ++i) {
    #pragma unroll
    for (int reg = 0; reg < 4; ++reg) {
      int n = n0 + m0 + i * 16 + quad * 4 + reg;
      float pr = 0.f;
      #pragma unroll
      for (int jj = 0; jj < 4; ++jj) pr = fmaf(acc[i][jj][reg], arw_l[jj], pr);
      #pragma unroll
      for (int off = 1; off < 16; off <<= 1) pr += __shfl_xor(pr, off);
      const float w = __expf(pr + arb);
      if (n < N) {
        if (lcol == 0) Wf[(size_t)n * 8 + h] = w;
        #pragma unroll
        for (int jj = 0; jj < 4; ++jj) {
          const int hp = h * 2 + (jj >> 1);
          u[((size_t)hp * NP1 + n) * 32 + (jj & 1) * 16 + lcol] =
              f2h(acc[i][jj][reg] * w);
        }
      }
    }
  }
}

// ---------------------------------------------------------------------------
// Zero the 16 per-slice dummy rows (index N of each slice). Must run after
// bsort (packed records alias u) and before agg.
// ---------------------------------------------------------------------------
__global__ __launch_bounds__(64) void zdum_kernel(short* __restrict__ u, int N)
{
  const int t = threadIdx.x;          // 64 threads = 16 slices x 4 uint4
  const int hp = t >> 2, q = t & 3;
  *(uint4*)(u + ((size_t)hp * (N + 1) + N) * 32 + q * 8) = make_uint4(0, 0, 0, 0);
}

// ---------------------------------------------------------------------------
// CSR build v2: bucket sort (line-dense writes; R8's atomic scatter had 16x
// write amplification).
// ---------------------------------------------------------------------------
__global__ __launch_bounds__(256) void bcount_kernel(
    const int* __restrict__ row, int* __restrict__ bcnt, int E)
{
  __shared__ int h[MAXB];
  for (int i = threadIdx.x; i < MAXB; i += 256) h[i] = 0;
  __syncthreads();
  for (int e = blockIdx.x * 256 + threadIdx.x; e < E; e += gridDim.x * 256)
    atomicAdd(&h[row[e] >> 7], 1);
  __syncthreads();
  for (int i = threadIdx.x; i < MAXB; i += 256) {
    int v = h[i];
    if (v) atomicAdd(&bcnt[i], v);
  }
}

__global__ __launch_bounds__(MAXB) void bscan_kernel(
    const int* __restrict__ bcnt, int* __restrict__ bofs,
    int* __restrict__ gcur, int* __restrict__ rowptr_last, int E, int NB)
{
  __shared__ int sd[MAXB];
  const int t = threadIdx.x;
  int v = (t < NB) ? bcnt[t] : 0;
  sd[t] = v;
  __syncthreads();
  for (int off = 1; off < MAXB; off <<= 1) {
    int u = (t >= off) ? sd[t - off] : 0;
    __syncthreads();
    sd[t] += u;
    __syncthreads();
  }
  int excl = sd[t] - v;
  if (t < NB) { bofs[t] = excl; gcur[t] = excl; }
  if (t == NB - 1) bofs[NB] = excl + v;   // == E
  if (t == 0) rowptr_last[0] = E;
}

__global__ __launch_bounds__(256) void bscatter_kernel(
    const int* __restrict__ row, const int* __restrict__ col,
    int* __restrict__ gcur, unsigned* __restrict__ packed, int E)
{
  __shared__ int h[MAXB];
  __shared__ int base[MAXB];
  const int lo = blockIdx.x * CHA;
  const int hi = min(lo + CHA, E);
  for (int i = threadIdx.x; i < MAXB; i += 256) h[i] = 0;
  __syncthreads();
  for (int e = lo + threadIdx.x; e < hi; e += 256)
    atomicAdd(&h[row[e] >> 7], 1);
  __syncthreads();
  for (int i = threadIdx.x; i < MAXB; i += 256) {
    int v = h[i];
    base[i] = v ? atomicAdd(&gcur[i], v) : 0;
    h[i] = 0;
  }
  __syncthreads();
  for (int e = lo + threadIdx.x; e < hi; e += 256) {
    int r = row[e];
    int b = r >> 7;
    int p = base[b] + atomicAdd(&h[b], 1);
    packed[p] = ((unsigned)(r & (RPB - 1)) << 16) | (unsigned)col[e];
  }
}

__global__ __launch_bounds__(256) void bsort_kernel(
    const unsigned* __restrict__ packed, const int* __restrict__ bofs,
    int* __restrict__ row_ptr, int* __restrict__ col_sorted, int N)
{
  __shared__ int h[RPB];
  __shared__ int sd[RPB];
  __shared__ int cur[RPB];
  const int b = blockIdx.x;
  const int lo = bofs[b], hi = bofs[b + 1];
  const int t = threadIdx.x;
  if (t < RPB) h[t] = 0;
  __syncthreads();
  for (int i = lo + t; i < hi; i += 256)
    atomicAdd(&h[packed[i] >> 16], 1);
  __syncthreads();
  if (t < RPB) sd[t] = h[t];
  __syncthreads();
  for (int off = 1; off < RPB; off <<= 1) {
    int u = (t >= off && t < RPB) ? sd[t - off] : 0;
    __syncthreads();
    if (t < RPB) sd[t] += u;
    __syncthreads();
  }
  if (t < RPB) {
    int excl = sd[t] - h[t];
    cur[t] = lo + excl;
    int r = b * RPB + t;
    if (r < N) row_ptr[r] = lo + excl;
  }
  __syncthreads();
  for (int i = lo + t; i < hi; i += 256) {
    unsigned u = packed[i];
    int p = atomicAdd(&cur[u >> 16], 1);
    col_sorted[p] = (int)(u & 0xffffu);
  }
}

// ---------------------------------------------------------------------------
// Denominator SpMV: swb[n][8] = sum_{j in N(n)} w[.][j]. Wf is 1.6MB ->
// L2-resident on every XCD; lane-per-edge, f32 accumulate, full-wave reduce.
// ---------------------------------------------------------------------------
__global__ __launch_bounds__(256) void sw_kernel(
    const int* __restrict__ row_ptr, const int* __restrict__ col_sorted,
    const float* __restrict__ Wf, float* __restrict__ swb, int N)
{
  const int lane = threadIdx.x & 63;
  const int wave = threadIdx.x >> 6;
  const int row = blockIdx.x * 4 + wave;
  if (row >= N) return;
  const int start = row_ptr[row], end = row_ptr[row + 1];
  float a[8];
  #pragma unroll
  for (int i = 0; i < 8; ++i) a[i] = 0.f;
  for (int e = start + lane; e < end; e += 64) {
    int c = col_sorted[e];
    const float4 v0 = *(const float4*)(Wf + (size_t)c * 8);
    const float4 v1 = *(const float4*)(Wf + (size_t)c * 8 + 4);
    a[0] += v0.x; a[1] += v0.y; a[2] += v0.z; a[3] += v0.w;
    a[4] += v1.x; a[5] += v1.y; a[6] += v1.z; a[7] += v1.w;
  }
  #pragma unroll
  for (int off = 1; off <= 32; off <<= 1) {
    #pragma unroll
    for (int i = 0; i < 8; ++i) a[i] += __shfl_xor(a[i], off);
  }
  if (lane == 0) {
    float* sp = swb + (size_t)row * 8;
    *(float4*)sp       = make_float4(a[0], a[1], a[2], a[3]);
    *((float4*)sp + 1) = make_float4(a[4], a[5], a[6], a[7]);
  }
}

// ---------------------------------------------------------------------------
// Aggregation half-kernel: out[:, head, p*32:(p+1)*32] for head = blockIdx&7.
// Residency (R4): premultiplied u; per-XCD high-rate set = 3.2MB slice < 4MB.
// Work-per-wave (R5/R7): 16 rows/wave, one row per 4-lane group.
// LDS-staged indices (R8): wave's window staged with coalesced nt loads.
// R12 = R10's 2-edge depth-2 ping-pong (24 VGPR, occ 72% -- R11's 4-edge
// stages cost 40 VGPR / 55% occ, a net loss) + R11's maskless consume via
// the dummy row at index N (tail select happens in loadP: 1 cmp+cndmask per
// edge; consume is pure perm+fdot2, no AND masks / clamp-mins).
// ---------------------------------------------------------------------------
__global__ __launch_bounds__(256) void agg_kernel(
    const int* __restrict__ row_ptr, const int* __restrict__ col_sorted,
    const unsigned short* __restrict__ u, const float* __restrict__ swb,
    const float* __restrict__ Wb, float* __restrict__ out, int N, int p)
{
  __shared__ int ec[4][CAPP];
  const int lane = threadIdx.x & 63;
  const int wave = threadIdx.x >> 6;
  const int head = blockIdx.x & 7;               // XCD pin (round-robin %8)
  const int g = lane >> 2, sub = lane & 3;
  const int rbase = ((blockIdx.x >> 3) * 4 + wave) * 16;
  const int row = rbase + g;
  const bool valid = row < N;
  const int NP1 = N + 1;

  // stage the wave's contiguous edge window into LDS (coalesced nt loads)
  const int wstart = row_ptr[min(rbase, N)];
  const int wend   = row_ptr[min(rbase + 16, N)];
  const int wlen = wend - wstart;
  const int nst = min(wlen, CAP);
  int* lds = ec[wave];
  for (int i = lane; i < nst; i += 64)
    lds[i] = __builtin_nontemporal_load(col_sorted + wstart + i);
  __syncthreads();

  const int sg = valid ? row_ptr[row]     : 0;
  const int eg = valid ? row_ptr[row + 1] : 0;
  const int deg = eg - sg;
  const unsigned short* ub =
      u + ((size_t)(head * 2 + p) * NP1) * 32 + (sub << 3);

  float acc[8];
  #pragma unroll
  for (int i = 0; i < 8; ++i) acc[i] = 0.f;
  const f16x2 ones = {(_Float16)1.0f, (_Float16)1.0f};

  if (wlen <= CAP) {
    const int lsg = valid ? sg - wstart : 0;
    const int np = (deg + 1) >> 1;
    const int nit2 = max(2, (np + 1) & ~1);   // even, >= 2

    auto loadP = [&](int jj, int& c1, int& c2) {
      const int b = lsg + 2 * jj;
      const int v1 = lds[b], v2 = lds[b + 1];  // CAPP padding: safe over-read
      c1 = (2 * jj     < deg) ? v1 : N;        // dummy row for tail/overrun
      c2 = (2 * jj + 1 < deg) ? v2 : N;
    };
    auto issueP = [&](int c1, int c2, uint4& v1, uint4& v2) {
      v1 = *(const uint4*)(ub + (size_t)c1 * 32);
      v2 = *(const uint4*)(ub + (size_t)c2 * 32);
    };
    auto consume = [&](const uint4& v1, const uint4& v2) {
      unsigned a1[4] = { v1.x, v1.y, v1.z, v1.w };
      unsigned a2[4] = { v2.x, v2.y, v2.z, v2.w };
      #pragma unroll
      for (int q = 0; q < 4; ++q) {
        unsigned plo = __builtin_amdgcn_perm(a2[q], a1[q], 0x05040100u);
        unsigned phi = __builtin_amdgcn_perm(a2[q], a1[q], 0x07060302u);
        acc[2 * q]     = __builtin_amdgcn_fdot2(u2h2(plo), ones, acc[2 * q],     false);
        acc[2 * q + 1] = __builtin_amdgcn_fdot2(u2h2(phi), ones, acc[2 * q + 1], false);
      }
    };

    int cA1, cA2, cB1, cB2;
    uint4 vA1, vA2, vB1, vB2;
    loadP(0, cA1, cA2); issueP(cA1, cA2, vA1, vA2);
    loadP(1, cB1, cB2); issueP(cB1, cB2, vB1, vB2);
    int j = 0;
    for (; j + 2 < nit2; j += 2) {
      consume(vA1, vA2);
      loadP(j + 2, cA1, cA2); issueP(cA1, cA2, vA1, vA2);
      consume(vB1, vB2);
      loadP(j + 3, cB1, cB2); issueP(cB1, cB2, vB1, vB2);
    }
    consume(vA1, vA2);
    consume(vB1, vB2);
  } else {
    // fallback (window > CAP; statistically impossible but correct)
    const int np = (deg + 1) >> 1;
    for (int j = 0; j < np; ++j) {
      const int e1 = sg + 2 * j, e2 = e1 + 1;
      const int c1 = (e1 < eg) ? __builtin_nontemporal_load(col_sorted + e1) : N;
      const int c2 = (e2 < eg) ? __builtin_nontemporal_load(col_sorted + e2) : N;
      const uint4 v1 = *(const uint4*)(ub + (size_t)c1 * 32);
      const uint4 v2 = *(const uint4*)(ub + (size_t)c2 * 32);
      unsigned a1[4] = { v1.x, v1.y, v1.z, v1.w };
      unsigned a2[4] = { v2.x, v2.y, v2.z, v2.w };
      #pragma unroll
      for (int q = 0; q < 4; ++q) {
        unsigned plo = __builtin_amdgcn_perm(a2[q], a1[q], 0x05040100u);
        unsigned phi = __builtin_amdgcn_perm(a2[q], a1[q], 0x07060302u);
        acc[2 * q]     = __builtin_amdgcn_fdot2(u2h2(plo), ones, acc[2 * q],     false);
        acc[2 * q + 1] = __builtin_amdgcn_fdot2(u2h2(phi), ones, acc[2 * q + 1], false);
      }
    }
  }

  if (valid) {
    const float sw = swb[(size_t)row * 8 + head];
    const float inv = (sw > 0.f) ? 1.f / sw : 0.f;
    const int bidx = head * OUT + p * 32 + (sub << 3);
    const float4 b0 = *(const float4*)(Wb + bidx);
    const float4 b1 = *(const float4*)(Wb + bidx + 4);
    const float bb[8] = { b0.x, b0.y, b0.z, b0.w, b1.x, b1.y, b1.z, b1.w };
    float r[8];
    #pragma unroll
    for (int i = 0; i < 8; ++i) {
      float y = acc[i] * inv + bb[i];
      r[i] = (y > 0.f) ? y : (__expf(y) - 1.f);
    }
    f32x4* op = (f32x4*)(out + (size_t)row * NOUT + bidx);
    f32x4 o0 = { r[0], r[1], r[2], r[3] };
    f32x4 o1 = { r[4], r[5], r[6], r[7] };
    __builtin_nontemporal_store(o0, op);
    __builtin_nontemporal_store(o1, op + 1);
  }
}

// ---------------------------------------------------------------------------
extern "C" void kernel_launch(void* const* d_in, const int* in_sizes, int n_in,
                              void* d_out, int out_size, void* d_ws, size_t ws_size,
                              hipStream_t stream)
{
  const float* x    = (const float*)d_in[0];
  const int*   erow = (const int*)d_in[1];
  const int*   ecol = (const int*)d_in[2];
  const float* Ws   = (const float*)d_in[3];
  const float* Wb   = (const float*)d_in[4];
  const float* As   = (const float*)d_in[5];
  const float* Asb  = (const float*)d_in[6];
  float* out = (float*)d_out;
  const int N = in_sizes[0] / F_IN;
  const int E = in_sizes[1];

  char* p = (char*)d_ws;
  short* u       = (short*)p; p += (size_t)16 * (N + 1) * 32 * sizeof(short);
  short* xh      = (short*)p; p += (size_t)N * F_IN * sizeof(short);
  short* W2      = (short*)p; p += (size_t)NOUT * F_IN * sizeof(short);
  float* Wf      = (float*)p; p += (size_t)N * HEADS * sizeof(float);
  float* swb     = (float*)p; p += (size_t)N * HEADS * sizeof(float);
  int* row_ptr   = (int*)p;   p += (size_t)(N + 1) * sizeof(int);
  int* bcnt      = (int*)p;   p += MAXB * sizeof(int);
  int* bofs      = (int*)p;   p += (MAXB + 1) * sizeof(int);
  int* gcur      = (int*)p;   p += MAXB * sizeof(int);
  int* col_sorted= (int*)p;   p += (size_t)E * sizeof(int);
  // packed records alias u: dead before gemm_mfma/zdum write u (same stream)
  unsigned* packed = (unsigned*)u;

  const int NB = (N + RPB - 1) / RPB;   // 391 for N=50000 (<= MAXB)

  (void)hipMemsetAsync(bcnt, 0, MAXB * sizeof(int), stream);

  // CSR build v2 (bucket sort, line-dense writes)
  bcount_kernel<<<dim3(512), dim3(256), 0, stream>>>(erow, bcnt, E);
  bscan_kernel<<<dim3(1), dim3(MAXB), 0, stream>>>(
      bcnt, bofs, gcur, row_ptr + N, E, NB);
  bscatter_kernel<<<dim3((E + CHA - 1) / CHA), dim3(256), 0, stream>>>(
      erow, ecol, gcur, packed, E);
  bsort_kernel<<<dim3(NB), dim3(256), 0, stream>>>(
      packed, bofs, row_ptr, col_sorted, N);
  // zero per-slice dummy rows (after bsort: packed aliases u)
  zdum_kernel<<<dim3(1), dim3(64), 0, stream>>>(u, N);

  // f16 conversions
  conv_kernel<<<dim3((N * F_IN / 8 + 255) / 256), dim3(256), 0, stream>>>(
      x, xh, N * F_IN / 8);
  conv_kernel<<<dim3((NOUT * F_IN / 8 + 255) / 256), dim3(256), 0, stream>>>(
      Ws, W2, NOUT * F_IN / 8);

  // MFMA GEMM with fused attention weight -> pre-scaled u + Wf
  const int ytiles = (N + 127) / 128;
  const int YB = (ytiles + 7) / 8;
  gemm_mfma<<<dim3(8 * 8 * YB), dim3(256), 0, stream>>>(
      xh, W2, As, Asb, Wf, u, N);

  // denominators
  sw_kernel<<<dim3((N + 3) / 4), dim3(256), 0, stream>>>(
      row_ptr, col_sorted, Wf, swb, N);

  // aggregation: two sequential half-kernels, head->XCD pinned,
  // 16 rows per wave, LDS-staged indices, maskless dummy-row inner loop
  const int nblk = 8 * ((N + 63) / 64);
  agg_kernel<<<dim3(nblk), dim3(256), 0, stream>>>(
      row_ptr, col_sorted, (const unsigned short*)u, swb, Wb, out, N, 0);
  agg_kernel<<<dim3(nblk), dim3(256), 0, stream>>>(
      row_ptr, col_sorted, (const unsigned short*)u, swb, Wb, out, N, 1);
}